// Round 1
// baseline (163.434 us; speedup 1.0000x reference)
//
#include <hip/hip_runtime.h>

#define B_   1024
#define L_   2048
#define IND_ 64
#define H_   4
#define K_   64

// ---------------- prep 1: w_eff[b][h][i] = (1/4) * sum_d q[b,h,d] * Wh[i, h*16+d]
__global__ __launch_bounds__(64) void prep_weff_k(const float* __restrict__ target,
                                                  const float* __restrict__ Wq,
                                                  const float* __restrict__ Wh,
                                                  float* __restrict__ weff) {
  const int b = blockIdx.x;
  const int t = threadIdx.x;  // 0..63
  __shared__ float tgt[64];
  __shared__ double q[64];
  tgt[t] = target[b * 64 + t];
  __syncthreads();
  // q[a] for a = t  (a = h*16 + d)
  double acc = 0.0;
#pragma unroll
  for (int j = 0; j < 64; ++j) acc += (double)tgt[j] * (double)Wq[j * 64 + t];
  q[t] = acc;
  __syncthreads();
#pragma unroll
  for (int h = 0; h < H_; ++h) {
    double a2 = 0.0;
#pragma unroll
    for (int d = 0; d < 16; ++d) a2 += q[h * 16 + d] * (double)Wh[t * 64 + h * 16 + d];
    weff[((size_t)b * H_ + h) * 64 + t] = (float)(a2 * 0.25);  // fold 1/SCALE
  }
}

// ---------------- prep 2: M[h][i][j] = sum_d Wv[i, h*16+d] * Wo[h*16+d, j]
__global__ __launch_bounds__(256) void prep_M_k(const float* __restrict__ Wv,
                                                const float* __restrict__ Wo,
                                                float* __restrict__ M) {
  const int idx = blockIdx.x * 256 + threadIdx.x;  // 0..16383
  const int h = idx >> 12, i = (idx >> 6) & 63, j = idx & 63;
  double a = 0.0;
#pragma unroll
  for (int d = 0; d < 16; ++d)
    a += (double)Wv[i * 64 + h * 16 + d] * (double)Wo[(h * 16 + d) * 64 + j];
  M[idx] = (float)a;
}

// monotone float->uint key (order-preserving), and inverse
__device__ __forceinline__ unsigned f2key(float s) {
  unsigned u = __float_as_uint(s);
  return (u & 0x80000000u) ? ~u : (u | 0x80000000u);
}
__device__ __forceinline__ float key2f(unsigned k) {
  unsigned u = (k & 0x80000000u) ? (k & 0x7FFFFFFFu) : ~k;
  return __uint_as_float(u);
}

// ---------------- main kernel: one block per b; wave w handles head w
__global__ __launch_bounds__(256) void attn_main_k(const float* __restrict__ seq,
                                                   const int* __restrict__ mask,
                                                   const float* __restrict__ weff,
                                                   const float* __restrict__ M,
                                                   float* __restrict__ out) {
  __shared__ float stage[64 * 64];       // 16 KB, one 64-row tile, XOR-swizzled
  __shared__ float scores[H_][L_];       // 32 KB
  __shared__ int   sidx[H_][K_];
  __shared__ float sw[H_][K_];
  __shared__ float svec[H_][64];
  __shared__ float part[H_][64];

  const int b = blockIdx.x;
  const int tid = threadIdx.x;
  const int w = tid >> 6;   // wave id == head id
  const int ln = tid & 63;
  const float* __restrict__ seqb = seq + (size_t)b * (L_ * IND_);
  const int* __restrict__ maskb = mask + (size_t)b * L_;

  // per-lane copy of this head's effective weight vector (64 VGPRs)
  float wef[64];
  {
    const float* wp = weff + ((size_t)b * H_ + w) * 64;
#pragma unroll
    for (int i = 0; i < 64; ++i) wef[i] = wp[i];
  }

  // ---------- scoring: 32 tiles x 64 rows ----------
  for (int t = 0; t < 32; ++t) {
    // stage tile: chunk f -> row r=f/16, float4-col c=f%16, swizzled col c^(r&7)
#pragma unroll
    for (int k = 0; k < 4; ++k) {
      const int f = tid + (k << 8);
      const int r = f >> 4;
      const int c = f & 15;
      const float4 v =
          *reinterpret_cast<const float4*>(seqb + ((t << 6) + r) * 64 + (c << 2));
      *reinterpret_cast<float4*>(&stage[(r << 6) + ((c ^ (r & 7)) << 2)]) = v;
    }
    __syncthreads();
    {
      const int r = ln;  // one row per lane
      const float* rp = &stage[r << 6];
      const int rs = r & 7;
      float acc = 0.f;
#pragma unroll
      for (int c = 0; c < 16; ++c) {
        const float4 v = *reinterpret_cast<const float4*>(rp + ((c ^ rs) << 2));
        acc = fmaf(v.x, wef[4 * c + 0], acc);
        acc = fmaf(v.y, wef[4 * c + 1], acc);
        acc = fmaf(v.z, wef[4 * c + 2], acc);
        acc = fmaf(v.w, wef[4 * c + 3], acc);
      }
      const int l = (t << 6) + r;
      scores[w][l] = maskb[l] ? acc : -1e9f;  // exact -1e9f, matches reference
    }
    __syncthreads();
  }

  // ---------- selection (per wave): exact 64th-largest via bitwise binary search ----------
  unsigned kk[32];
  float smax;
  {
    float mx = -3.0e38f;
#pragma unroll
    for (int j = 0; j < 32; ++j) {
      const float s = scores[w][ln + (j << 6)];
      mx = fmaxf(mx, s);
      kk[j] = f2key(s);
    }
#pragma unroll
    for (int off = 32; off >= 1; off >>= 1) mx = fmaxf(mx, __shfl_xor(mx, off, 64));
    smax = mx;
  }
  unsigned lo = 0u, hi = 0xFFFFFFFFu;
  while (lo < hi) {  // find max t with count(key >= t) >= 64
    const unsigned span = hi - lo;
    const unsigned mid = lo + (span >> 1) + (span & 1u);
    int c = 0;
#pragma unroll
    for (int j = 0; j < 32; ++j) c += (kk[j] >= mid) ? 1 : 0;
#pragma unroll
    for (int off = 32; off >= 1; off >>= 1) c += __shfl_xor(c, off, 64);
    if (c >= K_) lo = mid; else hi = mid - 1;
  }
  const unsigned V = lo;
  int cg = 0;
#pragma unroll
  for (int j = 0; j < 32; ++j) cg += (kk[j] > V) ? 1 : 0;
#pragma unroll
  for (int off = 32; off >= 1; off >>= 1) cg += __shfl_xor(cg, off, 64);
  const int m = K_ - cg;  // #ties (==V) to take, lowest index first (lax.top_k stable)

  {
    const unsigned long long lmlt = (1ull << ln) - 1ull;
    int gbase = 0, etaken = 0;
#pragma unroll
    for (int j = 0; j < 32; ++j) {
      const unsigned key = kk[j];
      const int l = ln + (j << 6);  // lane order == index order within chunk
      const bool gt = key > V;
      const bool eq = key == V;
      const unsigned long long bgt = __ballot(gt);
      const unsigned long long beq = __ballot(eq);
      if (gt) {
        const int pos = gbase + __popcll(bgt & lmlt);
        sidx[w][pos] = l;
        sw[w][pos] = expf(key2f(key) - smax);
      }
      const int navail = __popcll(beq);
      const int take = min(m - etaken, navail);
      if (eq) {
        const int rk = __popcll(beq & lmlt);
        if (rk < take) {
          const int pos = 63 - (etaken + rk);  // ties fill from the back
          sidx[w][pos] = l;
          sw[w][pos] = expf(key2f(key) - smax);
        }
      }
      gbase += __popcll(bgt);
      etaken += take;
    }
  }

  // ---------- gather + softmax-weighted sum of raw seq rows ----------
  {
    const int cg4 = ln & 15;  // float4 column group
    const int rg = ln >> 4;   // row subgroup 0..3
    float4 sv = make_float4(0.f, 0.f, 0.f, 0.f);
    float z = 0.f;
#pragma unroll
    for (int j = 0; j < 16; ++j) {
      const int sl = (j << 2) + rg;
      const int idx = sidx[w][sl];
      const float wt = sw[w][sl];
      const float4 v =
          *reinterpret_cast<const float4*>(seqb + (size_t)idx * 64 + (cg4 << 2));
      sv.x = fmaf(wt, v.x, sv.x);
      sv.y = fmaf(wt, v.y, sv.y);
      sv.z = fmaf(wt, v.z, sv.z);
      sv.w = fmaf(wt, v.w, sv.w);
      z += wt;
    }
#pragma unroll
    for (int off = 16; off <= 32; off <<= 1) {
      sv.x += __shfl_xor(sv.x, off, 64);
      sv.y += __shfl_xor(sv.y, off, 64);
      sv.z += __shfl_xor(sv.z, off, 64);
      sv.w += __shfl_xor(sv.w, off, 64);
      z += __shfl_xor(z, off, 64);
    }
    if (rg == 0) {  // lanes 0..15 hold the reduced result
      const float inv = 1.f / z;  // z >= 1 (max entry has weight 1)
      svec[w][(cg4 << 2) + 0] = sv.x * inv;
      svec[w][(cg4 << 2) + 1] = sv.y * inv;
      svec[w][(cg4 << 2) + 2] = sv.z * inv;
      svec[w][(cg4 << 2) + 3] = sv.w * inv;
    }
  }
  __syncthreads();

  // ---------- epilogue: out[b,:] = sum_h svec_h @ M_h ----------
  {
    float o = 0.f;
    const float* __restrict__ Mh = M + (w << 12);
#pragma unroll
    for (int i = 0; i < 64; ++i) o = fmaf(svec[w][i], Mh[(i << 6) + ln], o);
    part[w][ln] = o;
  }
  __syncthreads();
  if (tid < 64)
    out[(size_t)b * 64 + tid] = part[0][tid] + part[1][tid] + part[2][tid] + part[3][tid];
}

extern "C" void kernel_launch(void* const* d_in, const int* in_sizes, int n_in,
                              void* d_out, int out_size, void* d_ws, size_t ws_size,
                              hipStream_t stream) {
  const float* target = (const float*)d_in[0];
  const float* seq    = (const float*)d_in[1];
  const int*   mask   = (const int*)d_in[2];
  const float* Wq     = (const float*)d_in[3];
  const float* Wh     = (const float*)d_in[4];
  const float* Wv     = (const float*)d_in[5];
  const float* Wo     = (const float*)d_in[6];
  float* out  = (float*)d_out;
  float* weff = (float*)d_ws;                   // B*H*64 floats = 1 MB
  float* M    = weff + (size_t)B_ * H_ * 64;    // H*64*64 floats = 64 KB

  prep_weff_k<<<B_, 64, 0, stream>>>(target, Wq, Wh, weff);
  prep_M_k<<<64, 256, 0, stream>>>(Wv, Wo, M);
  attn_main_k<<<B_, 256, 0, stream>>>(seq, mask, weff, M, out);
}